// Round 1
// baseline (252.355 us; speedup 1.0000x reference)
//
#include <hip/hip_runtime.h>
#include <hip/hip_bf16.h>

// ---------------- problem constants ----------------
#define NTOK   8192
#define TOPK   2
#define NROWS  (NTOK*TOPK)      // 16384
#define NEXP   8
#define KDIM   1024             // inner (INTER)
#define NDIM   2048             // output (HIDDEN)
#define MAX_TILES 136           // sum of ceil(cnt_e/128) <= 128+8

typedef __bf16 bf16_t;
typedef __bf16 bf16x8 __attribute__((ext_vector_type(8)));
typedef __bf16 bf16x4 __attribute__((ext_vector_type(4)));
typedef float  f32x4  __attribute__((ext_vector_type(4)));

static_assert(sizeof(bf16x8) == 16, "bf16x8 must be 16B");

// ---------------- ws layout (bytes) ----------------
#define OFF_TW    ((size_t)0)                    // 16384 f32 = 64KB
#define OFF_TIDS  ((size_t)(1<<16))              // 16384 i32 = 64KB
#define OFF_CNT   ((size_t)(1<<17))              // 8 i32
#define OFF_WL    ((size_t)((1<<17) + 1024))     // 136 * int4
#define OFF_RL    ((size_t)(1<<18))              // 8*16384 i32 = 512KB
#define OFF_XB    ((size_t)(1<<20))              // 16384*1024 bf16 = 32MB
#define OFF_WB    ((size_t)(34u<<20))            // 8*2048*1024 bf16 = 32MB
#define OFF_SCR   ((size_t)(68u<<20))            // scratch
#define NEED_F32  (OFF_SCR + (size_t)NROWS*NDIM*4)   // ~196MB
#define NEED_BF16 (OFF_SCR + (size_t)NROWS*NDIM*2)   // ~132MB

__device__ __forceinline__ void gload_lds16(const void* g, void* l) {
  __builtin_amdgcn_global_load_lds(
      (const __attribute__((address_space(1))) void*)g,
      (__attribute__((address_space(3))) void*)l, 16, 0, 0);
}

// ---------------- 1. routing: softmax + top2 ----------------
__global__ void routing_kernel(const float* __restrict__ logits,
                               float* __restrict__ tw, int* __restrict__ tids) {
  int t = blockIdx.x * blockDim.x + threadIdx.x;
  if (t >= NTOK) return;
  float4 a = *(const float4*)(logits + (size_t)t*NEXP);
  float4 b = *(const float4*)(logits + (size_t)t*NEXP + 4);
  float l[8] = {a.x, a.y, a.z, a.w, b.x, b.y, b.z, b.w};
  float m = l[0];
#pragma unroll
  for (int i = 1; i < 8; i++) m = fmaxf(m, l[i]);
  float p[8], s = 0.f;
#pragma unroll
  for (int i = 0; i < 8; i++) { p[i] = __expf(l[i] - m); s += p[i]; }
  // top-1 (lowest index on ties -> strict >)
  int e0 = 0; float b0 = p[0];
#pragma unroll
  for (int i = 1; i < 8; i++) if (p[i] > b0) { b0 = p[i]; e0 = i; }
  int e1 = (e0 == 0) ? 1 : 0; float b1 = p[e1];
#pragma unroll
  for (int i = 0; i < 8; i++) if (i != e0 && p[i] > b1) { b1 = p[i]; e1 = i; }
  float inv = 1.f / s;
  tw[2*t]   = b0 * inv; tids[2*t]   = e0;
  tw[2*t+1] = b1 * inv; tids[2*t+1] = e1;
}

// ---------------- 2. bucket rows by expert ----------------
__global__ void zero_cnt_kernel(int* cnt) {
  if (threadIdx.x < NEXP) cnt[threadIdx.x] = 0;
}
__global__ void bucket_kernel(const int* __restrict__ tids, int* __restrict__ cnt,
                              int* __restrict__ rowlist) {
  int r = blockIdx.x * blockDim.x + threadIdx.x;
  if (r >= NROWS) return;
  int e = tids[r];
  int pos = atomicAdd(&cnt[e], 1);
  rowlist[(size_t)e*NROWS + pos] = r;
}

// ---------------- 3. worklist of (expert,row-tile) ----------------
__global__ void build_wl_kernel(const int* __restrict__ cnt, int4* __restrict__ wl) {
  if (threadIdx.x != 0 || blockIdx.x != 0) return;
  int idx = 0;
  for (int e = 0; e < NEXP; e++) {
    int c = cnt[e];
    for (int rb = 0; rb < c; rb += 128) {
      int4 v; v.x = e; v.y = rb; v.z = (c - rb < 128) ? (c - rb) : 128; v.w = 0;
      wl[idx++] = v;
    }
  }
  for (; idx < MAX_TILES; idx++) { int4 v = {0,0,0,0}; wl[idx] = v; }
}

// ---------------- 4a. convert x -> bf16 ----------------
__global__ void cvt_x_kernel(const float* __restrict__ x, bf16_t* __restrict__ xb) {
  const int n4 = NROWS * KDIM / 4;
  int stride = gridDim.x * blockDim.x;
  for (int i = blockIdx.x * blockDim.x + threadIdx.x; i < n4; i += stride) {
    float4 v = ((const float4*)x)[i];
    bf16x4 o = { (bf16_t)v.x, (bf16_t)v.y, (bf16_t)v.z, (bf16_t)v.w };
    *(bf16x4*)(xb + (size_t)i*4) = o;
  }
}

// ---------------- 4b. convert+transpose w -> bf16 [E][N][K] ----------------
__global__ void cvt_w_kernel(const float* __restrict__ w, bf16_t* __restrict__ wb) {
  __shared__ bf16_t tile[32][36];   // [n][k], stride 72B (8B-aligned rows)
  int e  = blockIdx.z;
  int n0 = blockIdx.x * 32;
  int k0 = blockIdx.y * 32;
  int t  = threadIdx.x;
  int kr = t >> 3;            // 0..31  (k row)
  int nc = (t & 7) * 4;       // 0..28  (n col, 4 wide)
  const float* src = w + ((size_t)e * KDIM * NDIM) + (size_t)(k0 + kr) * NDIM + n0 + nc;
  float4 v = *(const float4*)src;
  tile[nc+0][kr] = (bf16_t)v.x;
  tile[nc+1][kr] = (bf16_t)v.y;
  tile[nc+2][kr] = (bf16_t)v.z;
  tile[nc+3][kr] = (bf16_t)v.w;
  __syncthreads();
  int nr = t >> 3;            // n row
  int kc = (t & 7) * 4;       // k col, 4 wide
  bf16x4 o = *(const bf16x4*)&tile[nr][kc];
  *(bf16x4*)(wb + ((size_t)e * NDIM * KDIM) + (size_t)(n0 + nr) * KDIM + k0 + kc) = o;
}

// ---------------- 5. grouped GEMM (m97 structure) ----------------
// tile 128x128, BK=32, 4 waves (each 64x64), mfma_f32_16x16x32_bf16
// MODE 0: fp32 scratch   MODE 1: bf16 scratch   MODE 2: atomic into out
template <int MODE>
__global__ __launch_bounds__(256)
void gemm_kernel(const bf16_t* __restrict__ xb,     // [NROWS][KDIM]
                 const bf16_t* __restrict__ wb,     // [NEXP][NDIM][KDIM]
                 const int*    __restrict__ rowlist,
                 const int4*   __restrict__ wl,
                 const float*  __restrict__ tw,
                 float*        __restrict__ scrf,
                 bf16_t*       __restrict__ scrb,
                 float*        __restrict__ outp) {
  __shared__ bf16_t As[128 * 32];   // [row][k]
  __shared__ bf16_t Bs[128 * 32];   // [n][k]   (B^T tile)

  int4 wle = wl[blockIdx.y];
  const int nrows = wle.z;
  if (nrows <= 0) return;
  const int e  = wle.x;
  const int n0 = blockIdx.x * 128;

  const int t    = threadIdx.x;
  const int lane = t & 63;
  const int wv   = t >> 6;

  // staging: thread t owns LDS rows t/4 (i=0) and 64+t/4 (i=1), k-slot (t&3)*8
  const int arow  = t >> 2;
  const int kslot = (t & 3) * 8;
  const int* rl = rowlist + (size_t)e * NROWS + wle.y;
  int r0 = rl[(arow      < nrows) ? arow      : (nrows - 1)];
  int r1 = rl[(64 + arow < nrows) ? 64 + arow : (nrows - 1)];

  const bf16_t* gA0 = xb + (size_t)r0 * KDIM + kslot;
  const bf16_t* gA1 = xb + (size_t)r1 * KDIM + kslot;
  const bf16_t* gB0 = wb + (size_t)e * NDIM * KDIM + (size_t)(n0 + arow) * KDIM + kslot;
  const bf16_t* gB1 = gB0 + (size_t)64 * KDIM;

  bf16_t* ldsA0 = &As[(0*256 + wv*64) * 8];
  bf16_t* ldsA1 = &As[(1*256 + wv*64) * 8];
  bf16_t* ldsB0 = &Bs[(0*256 + wv*64) * 8];
  bf16_t* ldsB1 = &Bs[(1*256 + wv*64) * 8];

  f32x4 acc[4][4] = {};

  const int wr  = (wv >> 1) * 64;   // wave row offset in tile
  const int wc  = (wv & 1) * 64;    // wave col offset in tile
  const int lr  = lane & 15;
  const int lkg = (lane >> 4) * 8;  // k-group start

  for (int k0 = 0; k0 < KDIM; k0 += 32) {
    __syncthreads();                 // previous reads done before overwrite
    gload_lds16(gA0, ldsA0);
    gload_lds16(gA1, ldsA1);
    gload_lds16(gB0, ldsB0);
    gload_lds16(gB1, ldsB1);
    gA0 += 32; gA1 += 32; gB0 += 32; gB1 += 32;
    __syncthreads();                 // drains vmcnt before use

    bf16x8 af[4], bfr[4];
#pragma unroll
    for (int mi = 0; mi < 4; mi++)
      af[mi] = *(const bf16x8*)&As[(wr + mi*16 + lr) * 32 + lkg];
#pragma unroll
    for (int ni = 0; ni < 4; ni++)
      bfr[ni] = *(const bf16x8*)&Bs[(wc + ni*16 + lr) * 32 + lkg];
#pragma unroll
    for (int mi = 0; mi < 4; mi++)
#pragma unroll
      for (int ni = 0; ni < 4; ni++)
        acc[mi][ni] = __builtin_amdgcn_mfma_f32_16x16x32_bf16(af[mi], bfr[ni], acc[mi][ni], 0, 0, 0);
  }

  // epilogue: C/D layout col = lane&15, row = (lane>>4)*4 + j
#pragma unroll
  for (int mi = 0; mi < 4; mi++) {
#pragma unroll
    for (int j = 0; j < 4; j++) {
      int rb = wr + mi*16 + (lane >> 4)*4 + j;
      if (rb < nrows) {
        int r = rl[rb];
        float s = tw[r];
        int col0 = n0 + wc + (lane & 15);
        if (MODE == 0) {
          float* dst = scrf + (size_t)r * NDIM + col0;
#pragma unroll
          for (int ni = 0; ni < 4; ni++) dst[ni*16] = acc[mi][ni][j] * s;
        } else if (MODE == 1) {
          bf16_t* dst = scrb + (size_t)r * NDIM + col0;
#pragma unroll
          for (int ni = 0; ni < 4; ni++) dst[ni*16] = (bf16_t)(acc[mi][ni][j] * s);
        } else {
          float* dst = outp + (size_t)(r >> 1) * NDIM + col0;
#pragma unroll
          for (int ni = 0; ni < 4; ni++) atomicAdd(dst + ni*16, acc[mi][ni][j] * s);
        }
      }
    }
  }
}

// ---------------- 6. pair reduce ----------------
__global__ void reduce_f32_kernel(const float* __restrict__ scr, float* __restrict__ out) {
  const int n4 = NTOK * NDIM / 4;   // float4 count
  int stride = gridDim.x * blockDim.x;
  for (int i = blockIdx.x * blockDim.x + threadIdx.x; i < n4; i += stride) {
    int tk = i >> 9;                // token (NDIM/4 = 512 float4 per row)
    int h  = i & 511;
    float4 a = ((const float4*)scr)[(size_t)tk*1024 + h];
    float4 b = ((const float4*)scr)[(size_t)tk*1024 + 512 + h];
    float4 o = {a.x+b.x, a.y+b.y, a.z+b.z, a.w+b.w};
    ((float4*)out)[i] = o;
  }
}
__global__ void reduce_bf16_kernel(const bf16_t* __restrict__ scr, float* __restrict__ out) {
  const int n4 = NTOK * NDIM / 4;
  int stride = gridDim.x * blockDim.x;
  for (int i = blockIdx.x * blockDim.x + threadIdx.x; i < n4; i += stride) {
    int tk = i >> 9;
    int h  = i & 511;
    bf16x4 a = ((const bf16x4*)scr)[(size_t)tk*1024 + h];
    bf16x4 b = ((const bf16x4*)scr)[(size_t)tk*1024 + 512 + h];
    float4 o = {(float)a[0] + (float)b[0], (float)a[1] + (float)b[1],
                (float)a[2] + (float)b[2], (float)a[3] + (float)b[3]};
    ((float4*)out)[i] = o;
  }
}

// ---------------- launch ----------------
extern "C" void kernel_launch(void* const* d_in, const int* in_sizes, int n_in,
                              void* d_out, int out_size, void* d_ws, size_t ws_size,
                              hipStream_t stream) {
  const float* x      = (const float*)d_in[0];
  const float* w      = (const float*)d_in[1];
  const float* logits = (const float*)d_in[2];
  float* out = (float*)d_out;

  char* ws = (char*)d_ws;
  float*  tw      = (float*)(ws + OFF_TW);
  int*    tids    = (int*)  (ws + OFF_TIDS);
  int*    cnt     = (int*)  (ws + OFF_CNT);
  int4*   wl      = (int4*) (ws + OFF_WL);
  int*    rowlist = (int*)  (ws + OFF_RL);
  bf16_t* xb      = (bf16_t*)(ws + OFF_XB);
  bf16_t* wb      = (bf16_t*)(ws + OFF_WB);
  float*  scrf    = (float*) (ws + OFF_SCR);
  bf16_t* scrb    = (bf16_t*)(ws + OFF_SCR);

  routing_kernel<<<NTOK/256, 256, 0, stream>>>(logits, tw, tids);
  zero_cnt_kernel<<<1, 64, 0, stream>>>(cnt);
  bucket_kernel<<<NROWS/256, 256, 0, stream>>>(tids, cnt, rowlist);
  build_wl_kernel<<<1, 64, 0, stream>>>(cnt, wl);
  cvt_x_kernel<<<2048, 256, 0, stream>>>(x, xb);
  cvt_w_kernel<<<dim3(NDIM/32, KDIM/32, NEXP), 256, 0, stream>>>(w, wb);

  dim3 ggrid(NDIM/128, MAX_TILES);
  if (ws_size >= NEED_F32) {
    gemm_kernel<0><<<ggrid, 256, 0, stream>>>(xb, wb, rowlist, wl, tw, scrf, nullptr, nullptr);
    reduce_f32_kernel<<<2048, 256, 0, stream>>>(scrf, out);
  } else if (ws_size >= NEED_BF16) {
    gemm_kernel<1><<<ggrid, 256, 0, stream>>>(xb, wb, rowlist, wl, tw, nullptr, scrb, nullptr);
    reduce_bf16_kernel<<<2048, 256, 0, stream>>>(scrb, out);
  } else {
    hipMemsetAsync(d_out, 0, (size_t)NTOK * NDIM * sizeof(float), stream);
    gemm_kernel<2><<<ggrid, 256, 0, stream>>>(xb, wb, rowlist, wl, tw, nullptr, nullptr, out);
  }
}